// Round 3
// baseline (126.066 us; speedup 1.0000x reference)
//
#include <hip/hip_runtime.h>
#include <hip/hip_bf16.h>

#define NB   16384
#define ND   2048
#define NG   8
#define NR   6
#define NKC  48
#define NOUT 54
#define BM   32
#define KC   128
#define NCH  (ND / KC)          // 16 chunks
#define LROW 136                // shorts; 272B row stride (not 0 mod 128B)
#define MAXT (NB / BM + NG)     // 520 tiles max

typedef __attribute__((ext_vector_type(8))) short short8_t;
typedef __attribute__((ext_vector_type(4))) float f32x4;

__device__ __forceinline__ unsigned short f2bf(float x) {
    union { float f; unsigned u; } v; v.f = x;
    unsigned r = v.u + 0x7FFFu + ((v.u >> 16) & 1u);   // RNE
    return (unsigned short)(r >> 16);
}

__device__ __forceinline__ short8_t cvt8(float4 a, float4 b) {
    short8_t s;
    s[0] = (short)f2bf(a.x); s[1] = (short)f2bf(a.y);
    s[2] = (short)f2bf(a.z); s[3] = (short)f2bf(a.w);
    s[4] = (short)f2bf(b.x); s[5] = (short)f2bf(b.y);
    s[6] = (short)f2bf(b.z); s[7] = (short)f2bf(b.w);
    return s;
}

// ---- 2-pass path: histogram ----
__global__ void hist_kernel(const int* __restrict__ roi, int* __restrict__ counts) {
    int i = blockIdx.x * 256 + threadIdx.x;
    int g = roi[i];
    int lane = threadIdx.x & 63;
    #pragma unroll
    for (int gg = 0; gg < NG; ++gg) {
        unsigned long long m = __ballot(g == gg);
        if (m && lane == (int)(__ffsll((unsigned long long)m) - 1))
            atomicAdd(&counts[gg], (int)__popcll(m));
    }
}

// ---- 2-pass path: scatter into packed regions ----
__global__ void scatter_kernel(const int* __restrict__ roi, const int* __restrict__ counts,
                               int* __restrict__ ranks, int* __restrict__ perm) {
    int off[NG];
    int acc = 0;
    #pragma unroll
    for (int gg = 0; gg < NG; ++gg) { off[gg] = acc; acc += counts[gg]; }
    int i = blockIdx.x * 256 + threadIdx.x;
    int g = roi[i];
    int lane = threadIdx.x & 63;
    #pragma unroll
    for (int gg = 0; gg < NG; ++gg) {
        unsigned long long m = __ballot(g == gg);
        if (!m) continue;
        int leader = (int)(__ffsll((unsigned long long)m) - 1);
        int base = 0;
        if (lane == leader) base = atomicAdd(&ranks[gg], (int)__popcll(m));
        base = __shfl(base, leader);
        if (g == gg) {
            int rank = (int)__popcll(m & ((1ull << lane) - 1ull));
            perm[off[gg] + base + rank] = i;
        }
    }
}

// ---- 1-pass path: scatter into fixed per-group regions of stride NB ----
__global__ void scatter1_kernel(const int* __restrict__ roi, int* __restrict__ cnt,
                                int* __restrict__ perm) {
    int i = blockIdx.x * 256 + threadIdx.x;
    int g = roi[i];
    int lane = threadIdx.x & 63;
    #pragma unroll
    for (int gg = 0; gg < NG; ++gg) {
        unsigned long long m = __ballot(g == gg);
        if (!m) continue;
        int leader = (int)(__ffsll((unsigned long long)m) - 1);
        int base = 0;
        if (lane == leader) base = atomicAdd(&cnt[gg], (int)__popcll(m));
        base = __shfl(base, leader);
        if (g == gg) {
            int rank = (int)__popcll(m & ((1ull << lane) - 1ull));
            perm[gg * NB + base + rank] = i;
        }
    }
}

// ---- grouped skinny GEMM: A reg-double-buffered, B LDS-double-buffered ----
__launch_bounds__(256, 3)
__global__ void gemm_kernel(const float* __restrict__ feats,
                            const float* __restrict__ Wreg, const float* __restrict__ breg,
                            const float* __restrict__ Wcls, const float* __restrict__ bcls,
                            const int* __restrict__ counts, const int* __restrict__ perm,
                            float* __restrict__ out, int stride) {
    __shared__ __align__(16) short Bs[2][64][LROW];
    __shared__ int sRow[BM];

    int ts[NG + 1]; ts[0] = 0;
    int off[NG]; int acc = 0;
    #pragma unroll
    for (int gg = 0; gg < NG; ++gg) {
        int c = counts[gg];
        off[gg] = stride ? gg * stride : acc;
        acc += c;
        ts[gg + 1] = ts[gg] + (c + BM - 1) / BM;
    }
    int b = blockIdx.x;
    if (b >= ts[NG]) return;
    int g = 0;
    #pragma unroll
    for (int gg = 0; gg < NG; ++gg) if (b >= ts[gg + 1]) g = gg + 1;
    int gcnt  = counts[g];
    int goff  = off[g];
    int rbase = (b - ts[g]) * BM;
    int nvalid = gcnt - rbase; if (nvalid > BM) nvalid = BM;

    int tid = threadIdx.x;
    if (tid < BM) {
        int r = rbase + tid;
        if (r >= gcnt) r = gcnt - 1;   // clamp; stores masked by nvalid
        sRow[tid] = perm[goff + r];
    }
    __syncthreads();

    // B staging role: thread t stages row t>>2, col-quarter t&3 (32 floats)
    int rB = tid >> 2;
    int cq = tid & 3;
    const float* wsrc = nullptr;
    if (rB < NR)        wsrc = Wreg + ((size_t)g * NR + rB) * ND + cq * 32;
    else if (rB < NOUT) wsrc = Wcls + ((size_t)g * NKC + (rB - NR)) * ND + cq * 32;

    // wave/frag roles: 4 waves = 2 m-halves x 2 n-halves
    int w = tid >> 6, l = tid & 63, lr = l & 15, lq = l >> 4;
    int mt = w & 1, nh = w >> 1;
    const float* aptr = feats + (size_t)sRow[mt * 16 + lr] * ND + lq * 8;
    const short* brp = (const short*)&Bs[0][0][0] + (nh * 32 + lr) * LROW + lq * 8;

    f32x4 acc0 = {0, 0, 0, 0}, acc1 = {0, 0, 0, 0};
    float4 ab[2][8];   // A double buffer (statically indexed via full unroll)
    float4 rb[8];      // B stage regs

    // ---- prologue: chunk 0 ----
    #pragma unroll
    for (int i = 0; i < 4; ++i) {
        ab[0][2 * i]     = *(const float4*)(aptr + i * 32);
        ab[0][2 * i + 1] = *(const float4*)(aptr + i * 32 + 4);
    }
    if (wsrc) {
        #pragma unroll
        for (int i = 0; i < 8; ++i) rb[i] = *(const float4*)(wsrc + 4 * i);
    } else {
        #pragma unroll
        for (int i = 0; i < 8; ++i) rb[i] = make_float4(0.f, 0.f, 0.f, 0.f);
    }
    {
        short* bw = &Bs[0][rB][cq * 32];
        #pragma unroll
        for (int j = 0; j < 4; ++j) *(short8_t*)(bw + 8 * j) = cvt8(rb[2 * j], rb[2 * j + 1]);
    }
    __syncthreads();

    // ---- main loop: 1 barrier per chunk ----
    #pragma unroll
    for (int c = 0; c < NCH; ++c) {
        const int cur = c & 1, nxt = cur ^ 1;
        if (c + 1 < NCH) {
            const float* ap = aptr + (c + 1) * KC;
            #pragma unroll
            for (int i = 0; i < 4; ++i) {
                ab[nxt][2 * i]     = *(const float4*)(ap + i * 32);
                ab[nxt][2 * i + 1] = *(const float4*)(ap + i * 32 + 4);
            }
            if (wsrc) {
                const float* s = wsrc + (c + 1) * KC;
                #pragma unroll
                for (int i = 0; i < 8; ++i) rb[i] = *(const float4*)(s + 4 * i);
            }
        }
        // compute chunk c: A from regs (cvt in-flight), B from LDS
        const short* bp = brp + cur * (64 * LROW);
        #pragma unroll
        for (int ks = 0; ks < 4; ++ks) {
            short8_t af = cvt8(ab[cur][2 * ks], ab[cur][2 * ks + 1]);
            short8_t b0 = *(const short8_t*)(bp + ks * 32);
            short8_t b1 = *(const short8_t*)(bp + 16 * LROW + ks * 32);
            acc0 = __builtin_amdgcn_mfma_f32_16x16x32_bf16(af, b0, acc0, 0, 0, 0);
            acc1 = __builtin_amdgcn_mfma_f32_16x16x32_bf16(af, b1, acc1, 0, 0, 0);
        }
        // write next chunk's B into the other buffer, then one barrier
        if (c + 1 < NCH) {
            short* bw = &Bs[nxt][rB][cq * 32];
            #pragma unroll
            for (int j = 0; j < 4; ++j) *(short8_t*)(bw + 8 * j) = cvt8(rb[2 * j], rb[2 * j + 1]);
        }
        __syncthreads();
    }

    // ---- epilogue: bias + scatter to routed rows ----
    const int B6 = NB * NR;
    #pragma unroll
    for (int n = 0; n < 2; ++n) {
        f32x4 v = n ? acc1 : acc0;
        int col = nh * 32 + n * 16 + lr;
        if (col < NOUT) {
            #pragma unroll
            for (int j = 0; j < 4; ++j) {
                int row = mt * 16 + lq * 4 + j;
                if (row < nvalid) {
                    int smp = sRow[row];
                    if (col < NR) out[smp * NR + col] = v[j] + breg[g * NR + col];
                    else          out[B6 + smp * NKC + (col - NR)] = v[j] + bcls[g * NKC + (col - NR)];
                }
            }
        }
    }
}

// ---- fallback (ws too small): exact fp32, one wave per sample ----
__global__ void fallback_kernel(const float* __restrict__ feats, const int* __restrict__ roi,
                                const float* __restrict__ Wreg, const float* __restrict__ breg,
                                const float* __restrict__ Wcls, const float* __restrict__ bcls,
                                float* __restrict__ out) {
    int i = blockIdx.x;
    int lane = threadIdx.x;
    int g = roi[i];
    const float* frow = feats + (size_t)i * ND;
    float f[32];
    #pragma unroll
    for (int q = 0; q < 32; ++q) f[q] = frow[lane + 64 * q];
    for (int o = 0; o < NOUT; ++o) {
        const float* wrow = (o < NR) ? Wreg + ((size_t)g * NR + o) * ND
                                     : Wcls + ((size_t)g * NKC + (o - NR)) * ND;
        float p = 0.f;
        #pragma unroll
        for (int q = 0; q < 32; ++q) p += f[q] * wrow[lane + 64 * q];
        #pragma unroll
        for (int s = 32; s; s >>= 1) p += __shfl_xor(p, s);
        if (lane == 0) {
            if (o < NR) out[i * NR + o] = p + breg[g * NR + o];
            else        out[NB * NR + i * NKC + (o - NR)] = p + bcls[g * NKC + (o - NR)];
        }
    }
}

extern "C" void kernel_launch(void* const* d_in, const int* in_sizes, int n_in,
                              void* d_out, int out_size, void* d_ws, size_t ws_size,
                              hipStream_t stream) {
    const float* feats = (const float*)d_in[0];
    const int*   roi   = (const int*)d_in[1];
    const float* Wreg  = (const float*)d_in[2];
    const float* breg  = (const float*)d_in[3];
    const float* Wcls  = (const float*)d_in[4];
    const float* bcls  = (const float*)d_in[5];
    float* out = (float*)d_out;

    size_t need1 = (size_t)(64 + NG * NB) * sizeof(int);   // 1-pass: fixed-stride perm
    size_t need2 = (size_t)(64 + NB) * sizeof(int);        // 2-pass: packed perm

    if (ws_size >= need1) {
        int* cnt  = (int*)d_ws;
        int* perm = cnt + 64;
        hipMemsetAsync(cnt, 0, 8 * sizeof(int), stream);
        scatter1_kernel<<<NB / 256, 256, 0, stream>>>(roi, cnt, perm);
        gemm_kernel<<<MAXT, 256, 0, stream>>>(feats, Wreg, breg, Wcls, bcls, cnt, perm, out, NB);
    } else if (ws_size >= need2) {
        int* counts = (int*)d_ws;
        int* ranks  = counts + 8;
        int* perm   = counts + 64;
        hipMemsetAsync(counts, 0, 16 * sizeof(int), stream);
        hist_kernel<<<NB / 256, 256, 0, stream>>>(roi, counts);
        scatter_kernel<<<NB / 256, 256, 0, stream>>>(roi, counts, ranks, perm);
        gemm_kernel<<<MAXT, 256, 0, stream>>>(feats, Wreg, breg, Wcls, bcls, counts, perm, out, 0);
    } else {
        fallback_kernel<<<NB, 64, 0, stream>>>(feats, roi, Wreg, breg, Wcls, bcls, out);
    }
}

// Round 4
// 84.834 us; speedup vs baseline: 1.4860x; 1.4860x over previous
//
#include <hip/hip_runtime.h>
#include <hip/hip_bf16.h>

#define NB   16384
#define ND   2048
#define NG   8
#define NR   6
#define NKC  48
#define NOUT 54
#define BM   32
#define KC   128
#define NCH  (ND / KC)            // 16 chunks
#define CHB  16384                // bytes per staged chunk image (A fp32 or B bf16)
#define LROW 136                  // (tier-3 fallback gemm)
#define MAXT (NB / BM + NG)       // 520 tiles max

typedef __attribute__((ext_vector_type(8))) short short8_t;
typedef __attribute__((ext_vector_type(4))) float f32x4;

__device__ __forceinline__ unsigned short f2bf(float x) {
    union { float f; unsigned u; } v; v.f = x;
    unsigned r = v.u + 0x7FFFu + ((v.u >> 16) & 1u);   // RNE
    return (unsigned short)(r >> 16);
}

__device__ __forceinline__ short8_t cvt8(float4 a, float4 b) {
    short8_t s;
    s[0] = (short)f2bf(a.x); s[1] = (short)f2bf(a.y);
    s[2] = (short)f2bf(a.z); s[3] = (short)f2bf(a.w);
    s[4] = (short)f2bf(b.x); s[5] = (short)f2bf(b.y);
    s[6] = (short)f2bf(b.z); s[7] = (short)f2bf(b.w);
    return s;
}

// hardware async global->LDS, 16B per lane; LDS dest is wave-uniform base + lane*16
__device__ __forceinline__ void gl_lds16(const void* g, void* s) {
    __builtin_amdgcn_global_load_lds(
        (const __attribute__((address_space(1))) void*)g,
        (__attribute__((address_space(3))) void*)s,
        16, 0, 0);
}

// ---- histogram (tier-2/3) ----
__global__ void hist_kernel(const int* __restrict__ roi, int* __restrict__ counts) {
    int i = blockIdx.x * 256 + threadIdx.x;
    int g = roi[i];
    int lane = threadIdx.x & 63;
    #pragma unroll
    for (int gg = 0; gg < NG; ++gg) {
        unsigned long long m = __ballot(g == gg);
        if (m && lane == (int)(__ffsll((unsigned long long)m) - 1))
            atomicAdd(&counts[gg], (int)__popcll(m));
    }
}

// ---- scatter into packed regions (tier-2/3) ----
__global__ void scatter_kernel(const int* __restrict__ roi, const int* __restrict__ counts,
                               int* __restrict__ ranks, int* __restrict__ perm) {
    int off[NG];
    int acc = 0;
    #pragma unroll
    for (int gg = 0; gg < NG; ++gg) { off[gg] = acc; acc += counts[gg]; }
    int i = blockIdx.x * 256 + threadIdx.x;
    int g = roi[i];
    int lane = threadIdx.x & 63;
    #pragma unroll
    for (int gg = 0; gg < NG; ++gg) {
        unsigned long long m = __ballot(g == gg);
        if (!m) continue;
        int leader = (int)(__ffsll((unsigned long long)m) - 1);
        int base = 0;
        if (lane == leader) base = atomicAdd(&ranks[gg], (int)__popcll(m));
        base = __shfl(base, leader);
        if (g == gg) {
            int rank = (int)__popcll(m & ((1ull << lane) - 1ull));
            perm[off[gg] + base + rank] = i;
        }
    }
}

// ---- 1-pass scatter into fixed per-group regions of stride NB (tier-1) ----
__global__ void scatter1_kernel(const int* __restrict__ roi, int* __restrict__ cnt,
                                int* __restrict__ perm) {
    int i = blockIdx.x * 256 + threadIdx.x;
    int g = roi[i];
    int lane = threadIdx.x & 63;
    #pragma unroll
    for (int gg = 0; gg < NG; ++gg) {
        unsigned long long m = __ballot(g == gg);
        if (!m) continue;
        int leader = (int)(__ffsll((unsigned long long)m) - 1);
        int base = 0;
        if (lane == leader) base = atomicAdd(&cnt[gg], (int)__popcll(m));
        base = __shfl(base, leader);
        if (g == gg) {
            int rank = (int)__popcll(m & ((1ull << lane) - 1ull));
            perm[gg * NB + base + rank] = i;
        }
    }
}

// ---- W -> bf16 blob: [g][chunk c][16KB LDS image], fragment-major, rows 54..63 zero ----
// granule gi: l = gi&63, q = (gi>>6)&15, c = (gi>>10)&15, g = gi>>14
// q = nh*8 + ks*2 + n; content = W[g][nh*32+n*16+(l&15)][c*128 + ks*32 + (l>>4)*8 .. +7]
__global__ void wconv_kernel(const float* __restrict__ Wreg, const float* __restrict__ Wcls,
                             short* __restrict__ Wbf) {
    int gi = blockIdx.x * 256 + threadIdx.x;          // 131072 granules
    int l  = gi & 63;
    int q  = (gi >> 6) & 15;
    int c  = (gi >> 10) & 15;
    int g  = gi >> 14;
    int nh = q >> 3, ks = (q >> 1) & 3, n = q & 1;
    int row = nh * 32 + n * 16 + (l & 15);
    int k   = c * 128 + ks * 32 + (l >> 4) * 8;
    short8_t v = {0, 0, 0, 0, 0, 0, 0, 0};
    if (row < NOUT) {
        const float* s = (row < NR) ? Wreg + (size_t)(g * NR + row) * ND + k
                                    : Wcls + (size_t)(g * NKC + row - NR) * ND + k;
        float4 a = *(const float4*)s;
        float4 b = *(const float4*)(s + 4);
        v = cvt8(a, b);
    }
    *(short8_t*)(Wbf + (size_t)gi * 8) = v;
}

// ---- primary GEMM: A & B staged via global_load_lds, fragment-major, double-buffered ----
__launch_bounds__(256, 2)
__global__ void gemm_lds_kernel(const float* __restrict__ feats,
                                const short* __restrict__ Wbf,
                                const float* __restrict__ breg, const float* __restrict__ bcls,
                                const int* __restrict__ counts, const int* __restrict__ perm,
                                float* __restrict__ out, int stride) {
    __shared__ __align__(16) char As[2][CHB];
    __shared__ __align__(16) char Bs[2][CHB];
    __shared__ int sRow[BM];

    int ts[NG + 1]; ts[0] = 0;
    int off[NG]; int acc = 0;
    #pragma unroll
    for (int gg = 0; gg < NG; ++gg) {
        int c = counts[gg];
        off[gg] = stride ? gg * stride : acc;
        acc += c;
        ts[gg + 1] = ts[gg] + (c + BM - 1) / BM;
    }
    int b = blockIdx.x;
    if (b >= ts[NG]) return;
    int g = 0;
    #pragma unroll
    for (int gg = 0; gg < NG; ++gg) if (b >= ts[gg + 1]) g = gg + 1;
    int gcnt  = counts[g];
    int goff  = off[g];
    int rbase = (b - ts[g]) * BM;
    int nvalid = gcnt - rbase; if (nvalid > BM) nvalid = BM;

    int tid = threadIdx.x;
    if (tid < BM) {
        int r = rbase + tid;
        if (r >= gcnt) r = gcnt - 1;   // clamp; stores masked by nvalid
        sRow[tid] = perm[goff + r];
    }
    __syncthreads();

    int w = tid >> 6, l = tid & 63, lr = l & 15, lq = l >> 4;
    int mt = w & 1, nh = w >> 1;      // compute roles

    // staging roles: wave w stages LDS granule-blocks q = 4w..4w+3 of each image
    // A image: offset(mt,ks,h,l) = mt*8192 + ks*2048 + h*1024 + l*16  (fp32)
    //   q=4w+i -> mtq = w>>1, ksq = (w&1)*2 + (i>>1), hq = i&1
    const float* aBase = feats + (size_t)sRow[(w >> 1) * 16 + lr] * ND + lq * 8;
    int ks0 = (w & 1) * 2;
    // B image: offset(nh,ks,n,l) = nh*8192 + (ks*2+n)*1024 + l*16  (bf16, blob = exact image)
    const short* bBlob = Wbf + (size_t)g * NCH * (CHB / 2) + w * 2048 + l * 8;

    f32x4 acc0 = {0, 0, 0, 0}, acc1 = {0, 0, 0, 0};

#define STAGE(cc, nb) do {                                                    \
        const float* ap_ = aBase + (cc) * KC;                                 \
        gl_lds16(ap_ + (ks0    ) * 32    , &As[nb][(w * 4 + 0) * 1024]);      \
        gl_lds16(ap_ + (ks0    ) * 32 + 4, &As[nb][(w * 4 + 1) * 1024]);      \
        gl_lds16(ap_ + (ks0 + 1) * 32    , &As[nb][(w * 4 + 2) * 1024]);      \
        gl_lds16(ap_ + (ks0 + 1) * 32 + 4, &As[nb][(w * 4 + 3) * 1024]);      \
        const short* bp_ = bBlob + (size_t)(cc) * (CHB / 2);                  \
        gl_lds16(bp_       , &Bs[nb][(w * 4 + 0) * 1024]);                    \
        gl_lds16(bp_ +  512, &Bs[nb][(w * 4 + 1) * 1024]);                    \
        gl_lds16(bp_ + 1024, &Bs[nb][(w * 4 + 2) * 1024]);                    \
        gl_lds16(bp_ + 1536, &Bs[nb][(w * 4 + 3) * 1024]);                    \
    } while (0)

    STAGE(0, 0);
    __syncthreads();

    #pragma unroll 2
    for (int c = 0; c < NCH; ++c) {
        int cb = c & 1;
        if (c + 1 < NCH) STAGE(c + 1, cb ^ 1);
        const float* aRd = (const float*)&As[cb][mt * 8192] + l * 4;
        const short* bRd = (const short*)&Bs[cb][nh * 8192] + l * 8;
        #pragma unroll
        for (int ks = 0; ks < 4; ++ks) {
            float4 a0 = *(const float4*)(aRd + ks * 512);
            float4 a1 = *(const float4*)(aRd + ks * 512 + 256);
            short8_t af = cvt8(a0, a1);
            short8_t b0 = *(const short8_t*)(bRd + ks * 1024);
            short8_t b1 = *(const short8_t*)(bRd + ks * 1024 + 512);
            acc0 = __builtin_amdgcn_mfma_f32_16x16x32_bf16(af, b0, acc0, 0, 0, 0);
            acc1 = __builtin_amdgcn_mfma_f32_16x16x32_bf16(af, b1, acc1, 0, 0, 0);
        }
        __syncthreads();
    }
#undef STAGE

    const int B6 = NB * NR;
    #pragma unroll
    for (int n = 0; n < 2; ++n) {
        f32x4 v = n ? acc1 : acc0;
        int col = nh * 32 + n * 16 + lr;
        if (col < NOUT) {
            #pragma unroll
            for (int j = 0; j < 4; ++j) {
                int row = mt * 16 + lq * 4 + j;
                if (row < nvalid) {
                    int smp = sRow[row];
                    if (col < NR) out[smp * NR + col] = v[j] + breg[g * NR + col];
                    else          out[B6 + smp * NKC + (col - NR)] = v[j] + bcls[g * NKC + (col - NR)];
                }
            }
        }
    }
}

// ---- tier-3 GEMM (proven R3 path, no Wbf needed) ----
__launch_bounds__(256, 3)
__global__ void gemm_kernel(const float* __restrict__ feats,
                            const float* __restrict__ Wreg, const float* __restrict__ breg,
                            const float* __restrict__ Wcls, const float* __restrict__ bcls,
                            const int* __restrict__ counts, const int* __restrict__ perm,
                            float* __restrict__ out, int stride) {
    __shared__ __align__(16) short Bsh[2][64][LROW];
    __shared__ int sRow[BM];

    int ts[NG + 1]; ts[0] = 0;
    int off[NG]; int acc = 0;
    #pragma unroll
    for (int gg = 0; gg < NG; ++gg) {
        int c = counts[gg];
        off[gg] = stride ? gg * stride : acc;
        acc += c;
        ts[gg + 1] = ts[gg] + (c + BM - 1) / BM;
    }
    int b = blockIdx.x;
    if (b >= ts[NG]) return;
    int g = 0;
    #pragma unroll
    for (int gg = 0; gg < NG; ++gg) if (b >= ts[gg + 1]) g = gg + 1;
    int gcnt  = counts[g];
    int goff  = off[g];
    int rbase = (b - ts[g]) * BM;
    int nvalid = gcnt - rbase; if (nvalid > BM) nvalid = BM;

    int tid = threadIdx.x;
    if (tid < BM) {
        int r = rbase + tid;
        if (r >= gcnt) r = gcnt - 1;
        sRow[tid] = perm[goff + r];
    }
    __syncthreads();

    int rB = tid >> 2;
    int cq = tid & 3;
    const float* wsrc = nullptr;
    if (rB < NR)        wsrc = Wreg + ((size_t)g * NR + rB) * ND + cq * 32;
    else if (rB < NOUT) wsrc = Wcls + ((size_t)g * NKC + (rB - NR)) * ND + cq * 32;

    int w = tid >> 6, l = tid & 63, lr = l & 15, lq = l >> 4;
    int mt = w & 1, nh = w >> 1;
    const float* aptr = feats + (size_t)sRow[mt * 16 + lr] * ND + lq * 8;
    const short* brp = (const short*)&Bsh[0][0][0] + (nh * 32 + lr) * LROW + lq * 8;

    f32x4 acc0 = {0, 0, 0, 0}, acc1 = {0, 0, 0, 0};
    float4 rb[8];

    if (wsrc) {
        #pragma unroll
        for (int i = 0; i < 8; ++i) rb[i] = *(const float4*)(wsrc + 4 * i);
    } else {
        #pragma unroll
        for (int i = 0; i < 8; ++i) rb[i] = make_float4(0.f, 0.f, 0.f, 0.f);
    }
    {
        short* bw = &Bsh[0][rB][cq * 32];
        #pragma unroll
        for (int j = 0; j < 4; ++j) *(short8_t*)(bw + 8 * j) = cvt8(rb[2 * j], rb[2 * j + 1]);
    }
    __syncthreads();

    #pragma unroll
    for (int c = 0; c < NCH; ++c) {
        const int cur = c & 1, nxt = cur ^ 1;
        if (c + 1 < NCH && wsrc) {
            const float* s = wsrc + (c + 1) * KC;
            #pragma unroll
            for (int i = 0; i < 8; ++i) rb[i] = *(const float4*)(s + 4 * i);
        }
        const short* bp = brp + cur * (64 * LROW);
        const float* ap = aptr + c * KC;
        #pragma unroll
        for (int ks = 0; ks < 4; ++ks) {
            float4 a0 = *(const float4*)(ap + ks * 32);
            float4 a1 = *(const float4*)(ap + ks * 32 + 4);
            short8_t af = cvt8(a0, a1);
            short8_t b0 = *(const short8_t*)(bp + ks * 32);
            short8_t b1 = *(const short8_t*)(bp + 16 * LROW + ks * 32);
            acc0 = __builtin_amdgcn_mfma_f32_16x16x32_bf16(af, b0, acc0, 0, 0, 0);
            acc1 = __builtin_amdgcn_mfma_f32_16x16x32_bf16(af, b1, acc1, 0, 0, 0);
        }
        if (c + 1 < NCH && wsrc) {
            short* bw = &Bsh[nxt][rB][cq * 32];
            #pragma unroll
            for (int j = 0; j < 4; ++j) *(short8_t*)(bw + 8 * j) = cvt8(rb[2 * j], rb[2 * j + 1]);
        } else if (c + 1 < NCH) {
            short8_t z = {0,0,0,0,0,0,0,0};
            short* bw = &Bsh[nxt][rB][cq * 32];
            #pragma unroll
            for (int j = 0; j < 4; ++j) *(short8_t*)(bw + 8 * j) = z;
        }
        __syncthreads();
    }

    const int B6 = NB * NR;
    #pragma unroll
    for (int n = 0; n < 2; ++n) {
        f32x4 v = n ? acc1 : acc0;
        int col = nh * 32 + n * 16 + lr;
        if (col < NOUT) {
            #pragma unroll
            for (int j = 0; j < 4; ++j) {
                int row = mt * 16 + lq * 4 + j;
                if (row < nvalid) {
                    int smp = sRow[row];
                    if (col < NR) out[smp * NR + col] = v[j] + breg[g * NR + col];
                    else          out[B6 + smp * NKC + (col - NR)] = v[j] + bcls[g * NKC + (col - NR)];
                }
            }
        }
    }
}

// ---- tier-4: exact fp32, one wave per sample ----
__global__ void fallback_kernel(const float* __restrict__ feats, const int* __restrict__ roi,
                                const float* __restrict__ Wreg, const float* __restrict__ breg,
                                const float* __restrict__ Wcls, const float* __restrict__ bcls,
                                float* __restrict__ out) {
    int i = blockIdx.x;
    int lane = threadIdx.x;
    int g = roi[i];
    const float* frow = feats + (size_t)i * ND;
    float f[32];
    #pragma unroll
    for (int q = 0; q < 32; ++q) f[q] = frow[lane + 64 * q];
    for (int o = 0; o < NOUT; ++o) {
        const float* wrow = (o < NR) ? Wreg + ((size_t)g * NR + o) * ND
                                     : Wcls + ((size_t)g * NKC + (o - NR)) * ND;
        float p = 0.f;
        #pragma unroll
        for (int q = 0; q < 32; ++q) p += f[q] * wrow[lane + 64 * q];
        #pragma unroll
        for (int s = 32; s; s >>= 1) p += __shfl_xor(p, s);
        if (lane == 0) {
            if (o < NR) out[i * NR + o] = p + breg[g * NR + o];
            else        out[NB * NR + i * NKC + (o - NR)] = p + bcls[g * NKC + (o - NR)];
        }
    }
}

extern "C" void kernel_launch(void* const* d_in, const int* in_sizes, int n_in,
                              void* d_out, int out_size, void* d_ws, size_t ws_size,
                              hipStream_t stream) {
    const float* feats = (const float*)d_in[0];
    const int*   roi   = (const int*)d_in[1];
    const float* Wreg  = (const float*)d_in[2];
    const float* breg  = (const float*)d_in[3];
    const float* Wcls  = (const float*)d_in[4];
    const float* bcls  = (const float*)d_in[5];
    float* out = (float*)d_out;

    const size_t wbfBytes = (size_t)NG * NCH * CHB;               // 2 MB blob
    const size_t need_t1 = wbfBytes + 256 + (size_t)NG * NB * 4;  // blob + 1-pass perm
    const size_t need_t2 = wbfBytes + 256 + (size_t)NB * 4;       // blob + 2-pass perm
    const size_t need_t3 = 256 + (size_t)NB * 4;                  // old path

    if (ws_size >= need_t1) {
        short* Wbf = (short*)d_ws;
        int* cnt  = (int*)((char*)d_ws + wbfBytes);
        int* perm = cnt + 64;
        hipMemsetAsync(cnt, 0, 8 * sizeof(int), stream);
        wconv_kernel<<<512, 256, 0, stream>>>(Wreg, Wcls, Wbf);
        scatter1_kernel<<<NB / 256, 256, 0, stream>>>(roi, cnt, perm);
        gemm_lds_kernel<<<MAXT, 256, 0, stream>>>(feats, Wbf, breg, bcls, cnt, perm, out, NB);
    } else if (ws_size >= need_t2) {
        short* Wbf = (short*)d_ws;
        int* counts = (int*)((char*)d_ws + wbfBytes);
        int* ranks  = counts + 8;
        int* perm   = counts + 64;
        hipMemsetAsync(counts, 0, 16 * sizeof(int), stream);
        wconv_kernel<<<512, 256, 0, stream>>>(Wreg, Wcls, Wbf);
        hist_kernel<<<NB / 256, 256, 0, stream>>>(roi, counts);
        scatter_kernel<<<NB / 256, 256, 0, stream>>>(roi, counts, ranks, perm);
        gemm_lds_kernel<<<MAXT, 256, 0, stream>>>(feats, Wbf, breg, bcls, counts, perm, out, 0);
    } else if (ws_size >= need_t3) {
        int* counts = (int*)d_ws;
        int* ranks  = counts + 8;
        int* perm   = counts + 64;
        hipMemsetAsync(counts, 0, 16 * sizeof(int), stream);
        hist_kernel<<<NB / 256, 256, 0, stream>>>(roi, counts);
        scatter_kernel<<<NB / 256, 256, 0, stream>>>(roi, counts, ranks, perm);
        gemm_kernel<<<MAXT, 256, 0, stream>>>(feats, Wreg, breg, Wcls, bcls, counts, perm, out, 0);
    } else {
        fallback_kernel<<<NB, 64, 0, stream>>>(feats, roi, Wreg, breg, Wcls, bcls, out);
    }
}

// Round 5
// 83.926 us; speedup vs baseline: 1.5021x; 1.0108x over previous
//
#include <hip/hip_runtime.h>
#include <hip/hip_bf16.h>

#define NB   16384
#define ND   2048
#define NG   8
#define NR   6
#define NKC  48
#define NOUT 54
#define KC2  64
#define NCH2 (ND / KC2)           // 32 chunks
#define NT16 (NB / 16 + NG)       // 1032 tiles of 16 samples
#define LROW 136                  // tier-3 fallback gemm
#define BM   32
#define KC   128
#define NCH  (ND / KC)
#define MAXT (NB / BM + NG)

typedef __attribute__((ext_vector_type(8))) short short8_t;
typedef __attribute__((ext_vector_type(4))) float f32x4;

__device__ __forceinline__ unsigned short f2bf(float x) {
    union { float f; unsigned u; } v; v.f = x;
    unsigned r = v.u + 0x7FFFu + ((v.u >> 16) & 1u);   // RNE
    return (unsigned short)(r >> 16);
}

__device__ __forceinline__ short8_t cvt8(float4 a, float4 b) {
    short8_t s;
    s[0] = (short)f2bf(a.x); s[1] = (short)f2bf(a.y);
    s[2] = (short)f2bf(a.z); s[3] = (short)f2bf(a.w);
    s[4] = (short)f2bf(b.x); s[5] = (short)f2bf(b.y);
    s[6] = (short)f2bf(b.z); s[7] = (short)f2bf(b.w);
    return s;
}

// ---- histogram (tier-3) ----
__global__ void hist_kernel(const int* __restrict__ roi, int* __restrict__ counts) {
    int i = blockIdx.x * 256 + threadIdx.x;
    int g = roi[i];
    int lane = threadIdx.x & 63;
    #pragma unroll
    for (int gg = 0; gg < NG; ++gg) {
        unsigned long long m = __ballot(g == gg);
        if (m && lane == (int)(__ffsll((unsigned long long)m) - 1))
            atomicAdd(&counts[gg], (int)__popcll(m));
    }
}

// ---- scatter into packed regions (tier-3) ----
__global__ void scatter_kernel(const int* __restrict__ roi, const int* __restrict__ counts,
                               int* __restrict__ ranks, int* __restrict__ perm) {
    int off[NG];
    int acc = 0;
    #pragma unroll
    for (int gg = 0; gg < NG; ++gg) { off[gg] = acc; acc += counts[gg]; }
    int i = blockIdx.x * 256 + threadIdx.x;
    int g = roi[i];
    int lane = threadIdx.x & 63;
    #pragma unroll
    for (int gg = 0; gg < NG; ++gg) {
        unsigned long long m = __ballot(g == gg);
        if (!m) continue;
        int leader = (int)(__ffsll((unsigned long long)m) - 1);
        int base = 0;
        if (lane == leader) base = atomicAdd(&ranks[gg], (int)__popcll(m));
        base = __shfl(base, leader);
        if (g == gg) {
            int rank = (int)__popcll(m & ((1ull << lane) - 1ull));
            perm[off[gg] + base + rank] = i;
        }
    }
}

// ---- 1-pass scatter into fixed per-group regions of stride NB (tier-1) ----
__global__ void scatter1_kernel(const int* __restrict__ roi, int* __restrict__ cnt,
                                int* __restrict__ perm) {
    int i = blockIdx.x * 256 + threadIdx.x;
    int g = roi[i];
    int lane = threadIdx.x & 63;
    #pragma unroll
    for (int gg = 0; gg < NG; ++gg) {
        unsigned long long m = __ballot(g == gg);
        if (!m) continue;
        int leader = (int)(__ffsll((unsigned long long)m) - 1);
        int base = 0;
        if (lane == leader) base = atomicAdd(&cnt[gg], (int)__popcll(m));
        base = __shfl(base, leader);
        if (g == gg) {
            int rank = (int)__popcll(m & ((1ull << lane) - 1ull));
            perm[gg * NB + base + rank] = i;
        }
    }
}

// ---- W -> bf16 blob, fragment-major for M=16 waves ----
// unit u (16B): l=u&63, q=(u>>6)&7, c=(u>>9)&31, g=u>>14; n=q>>1, ks=q&1
// content = W[g][n*16+(l&15)][c*64 + ks*32 + (l>>4)*8 .. +8)
__global__ void wconv_kernel(const float* __restrict__ Wreg, const float* __restrict__ Wcls,
                             short* __restrict__ Wbf) {
    int u = blockIdx.x * 256 + threadIdx.x;          // 131072 units
    int l = u & 63;
    int q = (u >> 6) & 7;
    int c = (u >> 9) & 31;
    int g = u >> 14;
    int n = q >> 1, ks = q & 1;
    int row = n * 16 + (l & 15);
    int k   = c * 64 + ks * 32 + (l >> 4) * 8;
    short8_t v = {0, 0, 0, 0, 0, 0, 0, 0};
    if (row < NOUT) {
        const float* s = (row < NR) ? Wreg + (size_t)(g * NR + row) * ND + k
                                    : Wcls + (size_t)(g * NKC + row - NR) * ND + k;
        float4 a = *(const float4*)s;
        float4 b = *(const float4*)(s + 4);
        v = cvt8(a, b);
    }
    *(short8_t*)(Wbf + (size_t)u * 8) = v;
}

// ---- primary: barrier-free register-fragment GEMM, M=16 per wave ----
__launch_bounds__(256, 2)
__global__ void gemm16_kernel(const float* __restrict__ feats,
                              const short* __restrict__ Wbf,
                              const float* __restrict__ breg, const float* __restrict__ bcls,
                              const int* __restrict__ counts, const int* __restrict__ perm,
                              float* __restrict__ out, int stride) {
    int tid = threadIdx.x, w = tid >> 6, l = tid & 63, lr = l & 15, lq = l >> 4;
    int t = blockIdx.x * 4 + w;

    int ts[NG + 1]; ts[0] = 0;
    int off[NG]; int acc_ = 0;
    #pragma unroll
    for (int gg = 0; gg < NG; ++gg) {
        int c = counts[gg];
        off[gg] = stride ? gg * stride : acc_;
        acc_ += c;
        ts[gg + 1] = ts[gg] + (c + 15) / 16;
    }
    if (t >= ts[NG]) return;
    int g = 0;
    #pragma unroll
    for (int gg = 0; gg < NG; ++gg) if (t >= ts[gg + 1]) g = gg + 1;
    int gcnt  = counts[g];
    int goff  = off[g];
    int rbase = (t - ts[g]) * 16;
    int nvalid = gcnt - rbase; if (nvalid > 16) nvalid = 16;

    int r = rbase + lr; if (r >= gcnt) r = gcnt - 1;   // clamp; stores masked later
    int smp = perm[goff + r];
    const float* aRow  = feats + (size_t)smp * ND;
    const short* bBase = Wbf + (size_t)g * 131072 + l * 8;

    f32x4 ac0 = {0,0,0,0}, ac1 = {0,0,0,0}, ac2 = {0,0,0,0}, ac3 = {0,0,0,0};
    float4   xa0, xa1, xa2, xa3, ya0, ya1, ya2, ya3;
    short8_t xb0, xb1, xb2, xb3, xb4, xb5, xb6, xb7;
    short8_t yb0, yb1, yb2, yb3, yb4, yb5, yb6, yb7;

#define LDA(p, cc) { const float* ap_ = aRow + (cc) * KC2 + lq * 8;            \
        p##0 = *(const float4*)(ap_);      p##1 = *(const float4*)(ap_ + 4);   \
        p##2 = *(const float4*)(ap_ + 32); p##3 = *(const float4*)(ap_ + 36); }
#define LDB(p, cc) { const short* bp_ = bBase + (size_t)(cc) * 4096;           \
        p##0 = *(const short8_t*)(bp_);        p##1 = *(const short8_t*)(bp_ + 512);  \
        p##2 = *(const short8_t*)(bp_ + 1024); p##3 = *(const short8_t*)(bp_ + 1536); \
        p##4 = *(const short8_t*)(bp_ + 2048); p##5 = *(const short8_t*)(bp_ + 2560); \
        p##6 = *(const short8_t*)(bp_ + 3072); p##7 = *(const short8_t*)(bp_ + 3584); }
#define CMP(a, b) { short8_t af0 = cvt8(a##0, a##1), af1 = cvt8(a##2, a##3);   \
        ac0 = __builtin_amdgcn_mfma_f32_16x16x32_bf16(af0, b##0, ac0, 0, 0, 0); \
        ac1 = __builtin_amdgcn_mfma_f32_16x16x32_bf16(af0, b##2, ac1, 0, 0, 0); \
        ac2 = __builtin_amdgcn_mfma_f32_16x16x32_bf16(af0, b##4, ac2, 0, 0, 0); \
        ac3 = __builtin_amdgcn_mfma_f32_16x16x32_bf16(af0, b##6, ac3, 0, 0, 0); \
        ac0 = __builtin_amdgcn_mfma_f32_16x16x32_bf16(af1, b##1, ac0, 0, 0, 0); \
        ac1 = __builtin_amdgcn_mfma_f32_16x16x32_bf16(af1, b##3, ac1, 0, 0, 0); \
        ac2 = __builtin_amdgcn_mfma_f32_16x16x32_bf16(af1, b##5, ac2, 0, 0, 0); \
        ac3 = __builtin_amdgcn_mfma_f32_16x16x32_bf16(af1, b##7, ac3, 0, 0, 0); }

    LDA(xa, 0); LDB(xb, 0);
    #pragma unroll
    for (int c = 0; c < NCH2; c += 2) {
        LDA(ya, c + 1); LDB(yb, c + 1);
        CMP(xa, xb);
        if (c + 2 < NCH2) { LDA(xa, c + 2); LDB(xb, c + 2); }
        CMP(ya, yb);
    }
#undef LDA
#undef LDB
#undef CMP

    const int B6 = NB * NR;
    #pragma unroll
    for (int n = 0; n < 4; ++n) {
        f32x4 v = (n == 0) ? ac0 : (n == 1) ? ac1 : (n == 2) ? ac2 : ac3;
        int col = n * 16 + lr;
        if (col < NOUT) {
            #pragma unroll
            for (int j = 0; j < 4; ++j) {
                int row = lq * 4 + j;
                if (row < nvalid) {
                    int s2 = perm[goff + rbase + row];
                    if (col < NR) out[s2 * NR + col] = v[j] + breg[g * NR + col];
                    else          out[B6 + s2 * NKC + (col - NR)] = v[j] + bcls[g * NKC + (col - NR)];
                }
            }
        }
    }
}

// ---- tier-3 GEMM (proven R3 path, no blob needed) ----
__launch_bounds__(256, 3)
__global__ void gemm_kernel(const float* __restrict__ feats,
                            const float* __restrict__ Wreg, const float* __restrict__ breg,
                            const float* __restrict__ Wcls, const float* __restrict__ bcls,
                            const int* __restrict__ counts, const int* __restrict__ perm,
                            float* __restrict__ out, int stride) {
    __shared__ __align__(16) short Bsh[2][64][LROW];
    __shared__ int sRow[BM];

    int ts[NG + 1]; ts[0] = 0;
    int off[NG]; int acc = 0;
    #pragma unroll
    for (int gg = 0; gg < NG; ++gg) {
        int c = counts[gg];
        off[gg] = stride ? gg * stride : acc;
        acc += c;
        ts[gg + 1] = ts[gg] + (c + BM - 1) / BM;
    }
    int b = blockIdx.x;
    if (b >= ts[NG]) return;
    int g = 0;
    #pragma unroll
    for (int gg = 0; gg < NG; ++gg) if (b >= ts[gg + 1]) g = gg + 1;
    int gcnt  = counts[g];
    int goff  = off[g];
    int rbase = (b - ts[g]) * BM;
    int nvalid = gcnt - rbase; if (nvalid > BM) nvalid = BM;

    int tid = threadIdx.x;
    if (tid < BM) {
        int r = rbase + tid;
        if (r >= gcnt) r = gcnt - 1;
        sRow[tid] = perm[goff + r];
    }
    __syncthreads();

    int rB = tid >> 2;
    int cq = tid & 3;
    const float* wsrc = nullptr;
    if (rB < NR)        wsrc = Wreg + ((size_t)g * NR + rB) * ND + cq * 32;
    else if (rB < NOUT) wsrc = Wcls + ((size_t)g * NKC + (rB - NR)) * ND + cq * 32;

    int w = tid >> 6, l = tid & 63, lr = l & 15, lq = l >> 4;
    int mt = w & 1, nh = w >> 1;
    const float* aptr = feats + (size_t)sRow[mt * 16 + lr] * ND + lq * 8;
    const short* brp = (const short*)&Bsh[0][0][0] + (nh * 32 + lr) * LROW + lq * 8;

    f32x4 acc0 = {0, 0, 0, 0}, acc1 = {0, 0, 0, 0};
    float4 rb[8];

    if (wsrc) {
        #pragma unroll
        for (int i = 0; i < 8; ++i) rb[i] = *(const float4*)(wsrc + 4 * i);
    } else {
        #pragma unroll
        for (int i = 0; i < 8; ++i) rb[i] = make_float4(0.f, 0.f, 0.f, 0.f);
    }
    {
        short* bw = &Bsh[0][rB][cq * 32];
        #pragma unroll
        for (int j = 0; j < 4; ++j) *(short8_t*)(bw + 8 * j) = cvt8(rb[2 * j], rb[2 * j + 1]);
    }
    __syncthreads();

    #pragma unroll
    for (int c = 0; c < NCH; ++c) {
        const int cur = c & 1, nxt = cur ^ 1;
        if (c + 1 < NCH && wsrc) {
            const float* s = wsrc + (c + 1) * KC;
            #pragma unroll
            for (int i = 0; i < 8; ++i) rb[i] = *(const float4*)(s + 4 * i);
        }
        const short* bp = brp + cur * (64 * LROW);
        const float* ap = aptr + c * KC;
        #pragma unroll
        for (int ks = 0; ks < 4; ++ks) {
            float4 a0 = *(const float4*)(ap + ks * 32);
            float4 a1 = *(const float4*)(ap + ks * 32 + 4);
            short8_t af = cvt8(a0, a1);
            short8_t b0 = *(const short8_t*)(bp + ks * 32);
            short8_t b1 = *(const short8_t*)(bp + 16 * LROW + ks * 32);
            acc0 = __builtin_amdgcn_mfma_f32_16x16x32_bf16(af, b0, acc0, 0, 0, 0);
            acc1 = __builtin_amdgcn_mfma_f32_16x16x32_bf16(af, b1, acc1, 0, 0, 0);
        }
        if (c + 1 < NCH && wsrc) {
            short* bw = &Bsh[nxt][rB][cq * 32];
            #pragma unroll
            for (int j = 0; j < 4; ++j) *(short8_t*)(bw + 8 * j) = cvt8(rb[2 * j], rb[2 * j + 1]);
        } else if (c + 1 < NCH) {
            short8_t z = {0,0,0,0,0,0,0,0};
            short* bw = &Bsh[nxt][rB][cq * 32];
            #pragma unroll
            for (int j = 0; j < 4; ++j) *(short8_t*)(bw + 8 * j) = z;
        }
        __syncthreads();
    }

    const int B6 = NB * NR;
    #pragma unroll
    for (int n = 0; n < 2; ++n) {
        f32x4 v = n ? acc1 : acc0;
        int col = nh * 32 + n * 16 + lr;
        if (col < NOUT) {
            #pragma unroll
            for (int j = 0; j < 4; ++j) {
                int row = mt * 16 + lq * 4 + j;
                if (row < nvalid) {
                    int smp = sRow[row];
                    if (col < NR) out[smp * NR + col] = v[j] + breg[g * NR + col];
                    else          out[B6 + smp * NKC + (col - NR)] = v[j] + bcls[g * NKC + (col - NR)];
                }
            }
        }
    }
}

// ---- tier-4: exact fp32, one wave per sample ----
__global__ void fallback_kernel(const float* __restrict__ feats, const int* __restrict__ roi,
                                const float* __restrict__ Wreg, const float* __restrict__ breg,
                                const float* __restrict__ Wcls, const float* __restrict__ bcls,
                                float* __restrict__ out) {
    int i = blockIdx.x;
    int lane = threadIdx.x;
    int g = roi[i];
    const float* frow = feats + (size_t)i * ND;
    float f[32];
    #pragma unroll
    for (int q = 0; q < 32; ++q) f[q] = frow[lane + 64 * q];
    for (int o = 0; o < NOUT; ++o) {
        const float* wrow = (o < NR) ? Wreg + ((size_t)g * NR + o) * ND
                                     : Wcls + ((size_t)g * NKC + (o - NR)) * ND;
        float p = 0.f;
        #pragma unroll
        for (int q = 0; q < 32; ++q) p += f[q] * wrow[lane + 64 * q];
        #pragma unroll
        for (int s = 32; s; s >>= 1) p += __shfl_xor(p, s);
        if (lane == 0) {
            if (o < NR) out[i * NR + o] = p + breg[g * NR + o];
            else        out[NB * NR + i * NKC + (o - NR)] = p + bcls[g * NKC + (o - NR)];
        }
    }
}

extern "C" void kernel_launch(void* const* d_in, const int* in_sizes, int n_in,
                              void* d_out, int out_size, void* d_ws, size_t ws_size,
                              hipStream_t stream) {
    const float* feats = (const float*)d_in[0];
    const int*   roi   = (const int*)d_in[1];
    const float* Wreg  = (const float*)d_in[2];
    const float* breg  = (const float*)d_in[3];
    const float* Wcls  = (const float*)d_in[4];
    const float* bcls  = (const float*)d_in[5];
    float* out = (float*)d_out;

    const size_t wbfBytes = (size_t)NG * 131072 * 2;              // 2 MB blob
    const size_t need_t1 = wbfBytes + 256 + (size_t)NG * NB * 4;  // blob + 1-pass perm
    const size_t need_t3 = 256 + (size_t)NB * 4;                  // packed-perm path

    if (ws_size >= need_t1) {
        short* Wbf = (short*)d_ws;
        int* cnt  = (int*)((char*)d_ws + wbfBytes);
        int* perm = cnt + 64;
        hipMemsetAsync(cnt, 0, 8 * sizeof(int), stream);
        wconv_kernel<<<512, 256, 0, stream>>>(Wreg, Wcls, Wbf);
        scatter1_kernel<<<NB / 256, 256, 0, stream>>>(roi, cnt, perm);
        gemm16_kernel<<<(NT16 + 3) / 4, 256, 0, stream>>>(feats, Wbf, breg, bcls, cnt, perm, out, NB);
    } else if (ws_size >= need_t3) {
        int* counts = (int*)d_ws;
        int* ranks  = counts + 8;
        int* perm   = counts + 64;
        hipMemsetAsync(counts, 0, 16 * sizeof(int), stream);
        hist_kernel<<<NB / 256, 256, 0, stream>>>(roi, counts);
        scatter_kernel<<<NB / 256, 256, 0, stream>>>(roi, counts, ranks, perm);
        gemm_kernel<<<MAXT, 256, 0, stream>>>(feats, Wreg, breg, Wcls, bcls, counts, perm, out, 0);
    } else {
        fallback_kernel<<<NB, 64, 0, stream>>>(feats, roi, Wreg, breg, Wcls, bcls, out);
    }
}